// Round 13
// baseline (164.500 us; speedup 1.0000x reference)
//
#include <hip/hip_runtime.h>
#include <hip/hip_bf16.h>

#define N_NODES 131072
#define BATCH 128
#define H 256
#define NTILES (N_NODES / 64)   // 2048 tiles of 64 rows

typedef _Float16 half8 __attribute__((ext_vector_type(8)));
typedef _Float16 half4 __attribute__((ext_vector_type(4)));
typedef float floatx4 __attribute__((ext_vector_type(4)));

// ---------------------------------------------------------------------------
// Prep: blocks 0..31 pack W1 into MFMA fragment order (f16); blocks 32..159
// zero pacc (128*256); block 32 also zeros pz (128). Runs every call so the
// atomic accumulators start from zero on each graph replay.
// ---------------------------------------------------------------------------
__global__ __launch_bounds__(256) void prep_kernel(
    const float* __restrict__ W1, _Float16* __restrict__ W1p,
    float* __restrict__ pacc, float* __restrict__ pz)
{
    const int bid = blockIdx.x;
    const int tid = threadIdx.x;
    if (bid < 32) {
        const int g = bid * 256 + tid;          // [0, 8192)
        const int ct = g >> 9;
        const int ks = (g >> 6) & 7;
        const int l  = g & 63;
        const int k0 = ks * 32 + (l >> 4) * 8;
        const int col = ct * 16 + (l & 15);
        half8 h;
        #pragma unroll
        for (int j = 0; j < 8; ++j) h[j] = (_Float16)W1[(k0 + j) * H + col];
        reinterpret_cast<half8*>(W1p)[g] = h;
    } else {
        pacc[(bid - 32) * 256 + tid] = 0.f;     // 128*256 = 32768 exactly
        if (bid == 32 && tid < BATCH) pz[tid] = 0.f;
    }
}

// ---------------------------------------------------------------------------
// FUSED kernel, one 64-row tile per block, wave-per-row-strip mapping:
//   wave w computes rows [16w,16w+16) x ALL 256 cols (16 col-tiles).
//   -> all 4 waves load IDENTICAL B fragments per ks-step (L1-hit for 3/4)
//   -> score for a row completes in-wave: 16-lane shfl reduce, no LDS
//      round-trip, no cross-wave combine.
// SWIZZLE RULE (bug fixed from r12): the XOR swizzle must be applied to the
// COLUMN bits of the final byte offset: byte = row*512 + (colpart ^ swz).
// Precomputing (base ^ swz) and then ADDING colpart carries into the row
// field and reads the wrong rows.
// Max-free softmax (|score| <= ||W2||_1+|b2| ~ 13, exp f32-safe).
// ---------------------------------------------------------------------------
__global__ __launch_bounds__(256, 4) void fused_kernel(
    const float* __restrict__ X, const _Float16* __restrict__ W1p,
    const float* __restrict__ b1, const float* __restrict__ W2,
    const float* __restrict__ b2, const int* __restrict__ offsets,
    float* __restrict__ pacc, float* __restrict__ pz)
{
    __shared__ __align__(16) _Float16 Xs[64 * H];   // 32 KB, swizzled
    __shared__ float scL[64];
    __shared__ int offL[BATCH];

    const int tid = threadIdx.x;
    const int wave = tid >> 6;
    const int lane = tid & 63;

    // XCD-chunked bijective swizzle (2048 % 8 == 0): tiles of the same gap
    // co-locate on one XCD -> atomics + X stream stay L2-local.
    const int bid = (int)(blockIdx.x & 7) * (NTILES / 8) + (int)(blockIdx.x >> 3);
    const int t0 = bid * 64;

    if (tid < BATCH) offL[tid] = offsets[tid];

    // ---- 1. stage X tile (f32 -> f16, XOR-swizzled) ----
    {
        const float4* Xv = reinterpret_cast<const float4*>(X + (long long)t0 * H);
        #pragma unroll
        for (int i = 0; i < 8; ++i) {
            const int c = tid + i * 256;
            const int row = c >> 5;
            const int col8 = c & 31;
            float4 a  = Xv[row * 64 + col8 * 2];
            float4 bq = Xv[row * 64 + col8 * 2 + 1];
            half8 h;
            h[0] = (_Float16)a.x;  h[1] = (_Float16)a.y;
            h[2] = (_Float16)a.z;  h[3] = (_Float16)a.w;
            h[4] = (_Float16)bq.x; h[5] = (_Float16)bq.y;
            h[6] = (_Float16)bq.z; h[7] = (_Float16)bq.w;
            int byte = row * 512 + (col8 * 16 ^ ((row & 7) << 4));
            *reinterpret_cast<half8*>(reinterpret_cast<char*>(Xs) + byte) = h;
        }
    }
    __syncthreads();   // Xs + offL ready

    // ---- 2. MFMA: wave strip rows = [16*wave, 16*wave+16), cols all ----
    floatx4 acc[16];
    #pragma unroll
    for (int ct = 0; ct < 16; ++ct) acc[ct] = (floatx4){0.f, 0.f, 0.f, 0.f};

    const half8* Bv = reinterpret_cast<const half8*>(W1p) + lane;
    const int arow = wave * 16 + (lane & 15);
    const int aswz = (arow & 7) << 4;
    const char* XsRow = reinterpret_cast<const char*>(Xs) + arow * 512;
    const int acolbase = (lane >> 4) * 16;

    #pragma unroll 1
    for (int ks = 0; ks < 8; ++ks) {
        half8 af = *reinterpret_cast<const half8*>(
            XsRow + ((ks * 64 + acolbase) ^ aswz));
        // batch 1: col-tiles 0..7 (same addresses on all 4 waves -> L1)
        half8 bf[8];
        #pragma unroll
        for (int ct = 0; ct < 8; ++ct) bf[ct] = Bv[(ct * 8 + ks) * 64];
        #pragma unroll
        for (int ct = 0; ct < 8; ++ct)
            acc[ct] = __builtin_amdgcn_mfma_f32_16x16x32_f16(af, bf[ct], acc[ct], 0, 0, 0);
        // batch 2: col-tiles 8..15
        #pragma unroll
        for (int ct = 0; ct < 8; ++ct) bf[ct] = Bv[((ct + 8) * 8 + ks) * 64];
        #pragma unroll
        for (int ct = 0; ct < 8; ++ct)
            acc[ct + 8] = __builtin_amdgcn_mfma_f32_16x16x32_f16(af, bf[ct], acc[ct + 8], 0, 0, 0);
    }

    // ---- 3. epilogue: tanh + W2 dot, in-wave 16-lane reduce, exp -> scL ----
    float s[4] = {0.f, 0.f, 0.f, 0.f};
    #pragma unroll
    for (int ct = 0; ct < 16; ++ct) {
        const int col = ct * 16 + (lane & 15);
        const float b1c = b1[col];
        const float w2c = W2[col];
        #pragma unroll
        for (int reg = 0; reg < 4; ++reg) {
            const float x = acc[ct][reg] + b1c;
            const float t = 1.f - 2.f / (__expf(2.f * x) + 1.f);
            s[reg] = fmaf(t, w2c, s[reg]);
        }
    }
    #pragma unroll
    for (int off = 1; off < 16; off <<= 1)
        #pragma unroll
        for (int reg = 0; reg < 4; ++reg)
            s[reg] += __shfl_xor(s[reg], off);

    if ((lane & 15) == 0) {
        const float bias2 = b2[0];
        const int r0 = wave * 16 + (lane >> 4) * 4;
        #pragma unroll
        for (int reg = 0; reg < 4; ++reg)
            scL[r0 + reg] = __expf(s[reg] + bias2);
    }
    __syncthreads();

    // ---- 4. PV from LDS; per-gap per-wave atomics ----
    int g_lo, g_hi;
    {
        int node = t0;
        if (node < offL[0]) g_lo = -1;
        else {
            int lo = 0, hi = BATCH - 1;
            while (lo < hi) { int mid = (lo + hi + 1) >> 1; if (offL[mid] <= node) lo = mid; else hi = mid - 1; }
            g_lo = lo;
        }
        node = t0 + 63;
        if (node < offL[0]) g_hi = -1;
        else {
            int lo = 0, hi = BATCH - 1;
            while (lo < hi) { int mid = (lo + hi + 1) >> 1; if (offL[mid] <= node) lo = mid; else hi = mid - 1; }
            g_hi = lo;
        }
    }

    for (int g = (g_lo < 0 ? 0 : g_lo); g <= g_hi; ++g) {
        const int rs = max(t0, offL[g]);
        const int re = min(t0 + 64, (g == BATCH - 1) ? N_NODES : offL[g + 1]);

        float4 a4 = {0.f, 0.f, 0.f, 0.f};
        float z = 0.f;
        for (int i = rs + wave; i < re; i += 4) {
            const int r = i - t0;
            const float p = scL[r];
            const int byte = r * 512 + ((((lane >> 1) ^ (r & 7))) << 4) + (lane & 1) * 8;
            half4 xv = *reinterpret_cast<const half4*>(
                reinterpret_cast<const char*>(Xs) + byte);
            a4.x = fmaf(p, (float)xv[0], a4.x);
            a4.y = fmaf(p, (float)xv[1], a4.y);
            a4.z = fmaf(p, (float)xv[2], a4.z);
            a4.w = fmaf(p, (float)xv[3], a4.w);
            z += p;
        }
        // per-wave atomics (order-independent f32 adds)
        float* dst = &pacc[g * H + lane * 4];
        atomicAdd(dst + 0, a4.x);
        atomicAdd(dst + 1, a4.y);
        atomicAdd(dst + 2, a4.z);
        atomicAdd(dst + 3, a4.w);
        if (lane == 0) atomicAdd(&pz[g], z);
    }
}

// ---------------------------------------------------------------------------
// Reduce: segment b = union of gaps [max(b-1,0), min(b+1,127)].
// out = sum(acc_g) / sum(z_g). 128 blocks x 256 threads.
// ---------------------------------------------------------------------------
__global__ __launch_bounds__(256) void reduce_kernel(
    const float* __restrict__ pacc, const float* __restrict__ pz,
    float* __restrict__ out)
{
    const int b = blockIdx.x;
    const int tid = threadIdx.x;
    const int g0 = (b == 0) ? 0 : b - 1;
    const int g1 = (b >= BATCH - 1) ? BATCH - 1 : b + 1;

    float r = 0.f, z = 0.f;
    for (int g = g0; g <= g1; ++g) {
        r += pacc[g * H + tid];
        z += pz[g];
    }
    out[b * H + tid] = r / z;
}

// ---------------------------------------------------------------------------
extern "C" void kernel_launch(void* const* d_in, const int* in_sizes, int n_in,
                              void* d_out, int out_size, void* d_ws, size_t ws_size,
                              hipStream_t stream)
{
    const float* X     = (const float*)d_in[0];
    const int* offs    = (const int*)d_in[1];   // int64 in ref -> int32 on device
    const float* W1    = (const float*)d_in[2];
    const float* b1    = (const float*)d_in[3];
    const float* W2    = (const float*)d_in[4];
    const float* b2    = (const float*)d_in[5];
    float* out         = (float*)d_out;

    // workspace layout (floats):
    //   [0, 32768)        pacc   (128 gaps x 256)
    //   [32768, 32896)    pz     (128)
    //   [32896, ...)      W1p    (65536 f16 = 128 KB)
    float* pacc   = (float*)d_ws;
    float* pz     = pacc + BATCH * H;
    _Float16* W1p = (_Float16*)(pz + BATCH);

    prep_kernel<<<160, 256, 0, stream>>>(W1, W1p, pacc, pz);
    fused_kernel<<<NTILES, 256, 0, stream>>>(X, W1p, b1, W2, b2, offs, pacc, pz);
    reduce_kernel<<<BATCH, 256, 0, stream>>>(pacc, pz, out);
}

// Round 14
// 61.017 us; speedup vs baseline: 2.6960x; 2.6960x over previous
//
#include <hip/hip_runtime.h>
#include <hip/hip_bf16.h>

#define N_NODES 131072
#define BATCH 128
#define H 256
#define TROWS 32
#define NTILES (N_NODES / TROWS)   // 4096 tiles of 32 rows

typedef _Float16 half8 __attribute__((ext_vector_type(8)));
typedef _Float16 half4 __attribute__((ext_vector_type(4)));
typedef float floatx4 __attribute__((ext_vector_type(4)));

// ---------------------------------------------------------------------------
// Prep: blocks 0..31 pack W1 into MFMA fragment order (f16); blocks 32..159
// zero pacc (128*256); block 32 also zeros pz (128). Runs every call so the
// atomic accumulators start from zero on each graph replay.
// ---------------------------------------------------------------------------
__global__ __launch_bounds__(256) void prep_kernel(
    const float* __restrict__ W1, _Float16* __restrict__ W1p,
    float* __restrict__ pacc, float* __restrict__ pz)
{
    const int bid = blockIdx.x;
    const int tid = threadIdx.x;
    if (bid < 32) {
        const int g = bid * 256 + tid;          // [0, 8192)
        const int ct = g >> 9;
        const int ks = (g >> 6) & 7;
        const int l  = g & 63;
        const int k0 = ks * 32 + (l >> 4) * 8;
        const int col = ct * 16 + (l & 15);
        half8 h;
        #pragma unroll
        for (int j = 0; j < 8; ++j) h[j] = (_Float16)W1[(k0 + j) * H + col];
        reinterpret_cast<half8*>(W1p)[g] = h;
    } else {
        pacc[(bid - 32) * 256 + tid] = 0.f;     // 128*256 = 32768 exactly
        if (bid == 32 && tid < BATCH) pz[tid] = 0.f;
    }
}

// ---------------------------------------------------------------------------
// FUSED kernel, one 32-row tile per block (r11 structure, half-size tile for
// occupancy: LDS ~21.6KB -> 7 blocks/CU ~ 28 waves/CU).
//   wave w owns col-tiles [4w, 4w+4) (64 cols) x all 32 rows (2 row-tiles);
//   loads only its own 32KB B-quarter per tile (L1-friendly, r13 lesson).
// Phases: stage f32->f16 swizzled LDS -> MFMA (8 ks) -> tanh/W2 dot
//   (16-lane shfl + sp[] cross-wave combine) -> exp -> scL -> PV from LDS
//   -> accL combine -> ONE per-block atomic set per gap (r13 lesson).
// Max-free softmax (|score| <= ||W2||_1+|b2| ~ 13, exp f32-safe).
// ---------------------------------------------------------------------------
__global__ __launch_bounds__(256, 7) void fused_kernel(
    const float* __restrict__ X, const _Float16* __restrict__ W1p,
    const float* __restrict__ b1, const float* __restrict__ W2,
    const float* __restrict__ b2, const int* __restrict__ offsets,
    float* __restrict__ pacc, float* __restrict__ pz)
{
    __shared__ __align__(16) _Float16 Xs[TROWS * H];   // 16 KB, swizzled
    __shared__ float sp[4][TROWS];
    __shared__ float scL[TROWS];
    __shared__ float accL[4][H];
    __shared__ float zLs[4];
    __shared__ int offL[BATCH];

    const int tid = threadIdx.x;
    const int wave = tid >> 6;
    const int lane = tid & 63;

    // XCD-chunked bijective swizzle (4096 % 8 == 0)
    const int bid = (int)(blockIdx.x & 7) * (NTILES / 8) + (int)(blockIdx.x >> 3);
    const int t0 = bid * TROWS;

    if (tid < BATCH) offL[tid] = offsets[tid];

    // ---- 1. stage X tile (32 rows x 256 cols, f32 -> f16, XOR-swizzled) ----
    {
        const float4* Xv = reinterpret_cast<const float4*>(X + (long long)t0 * H);
        #pragma unroll
        for (int i = 0; i < 4; ++i) {
            const int c = tid + i * 256;        // 1024 half8-chunks
            const int row = c >> 5;
            const int col8 = c & 31;
            float4 a  = Xv[row * 64 + col8 * 2];
            float4 bq = Xv[row * 64 + col8 * 2 + 1];
            half8 h;
            h[0] = (_Float16)a.x;  h[1] = (_Float16)a.y;
            h[2] = (_Float16)a.z;  h[3] = (_Float16)a.w;
            h[4] = (_Float16)bq.x; h[5] = (_Float16)bq.y;
            h[6] = (_Float16)bq.z; h[7] = (_Float16)bq.w;
            int byte = row * 512 + (col8 * 16 ^ ((row & 7) << 4));
            *reinterpret_cast<half8*>(reinterpret_cast<char*>(Xs) + byte) = h;
        }
    }
    __syncthreads();   // Xs + offL ready

    // ---- 2. MFMA: wave w = col-tiles [4w,4w+4), rows = 2 row-tiles ----
    floatx4 acc[2][4];
    #pragma unroll
    for (int rt = 0; rt < 2; ++rt)
        #pragma unroll
        for (int ctl = 0; ctl < 4; ++ctl)
            acc[rt][ctl] = (floatx4){0.f, 0.f, 0.f, 0.f};

    const half8* Bw = reinterpret_cast<const half8*>(W1p) + wave * 2048 + lane;

    #pragma unroll 1
    for (int ks = 0; ks < 8; ++ks) {
        half8 bf0 = Bw[ks * 64];
        half8 bf1 = Bw[512 + ks * 64];
        half8 bf2 = Bw[1024 + ks * 64];
        half8 bf3 = Bw[1536 + ks * 64];
        half8 af[2];
        #pragma unroll
        for (int rt = 0; rt < 2; ++rt) {
            const int row = rt * 16 + (lane & 15);
            const int byte = row * 512 +
                ((ks * 64 + (lane >> 4) * 16) ^ ((row & 7) << 4));
            af[rt] = *reinterpret_cast<const half8*>(
                reinterpret_cast<const char*>(Xs) + byte);
        }
        #pragma unroll
        for (int rt = 0; rt < 2; ++rt) {
            acc[rt][0] = __builtin_amdgcn_mfma_f32_16x16x32_f16(af[rt], bf0, acc[rt][0], 0, 0, 0);
            acc[rt][1] = __builtin_amdgcn_mfma_f32_16x16x32_f16(af[rt], bf1, acc[rt][1], 0, 0, 0);
            acc[rt][2] = __builtin_amdgcn_mfma_f32_16x16x32_f16(af[rt], bf2, acc[rt][2], 0, 0, 0);
            acc[rt][3] = __builtin_amdgcn_mfma_f32_16x16x32_f16(af[rt], bf3, acc[rt][3], 0, 0, 0);
        }
    }

    // ---- 3. epilogue: tanh + W2 dot -> 16-lane reduce -> sp -> exp ----
    float w2v[4], b1v[4];
    #pragma unroll
    for (int ctl = 0; ctl < 4; ++ctl) {
        const int col = wave * 64 + ctl * 16 + (lane & 15);
        w2v[ctl] = W2[col];
        b1v[ctl] = b1[col];
    }

    float sc[2][4];
    #pragma unroll
    for (int rt = 0; rt < 2; ++rt) {
        #pragma unroll
        for (int reg = 0; reg < 4; ++reg) {
            float s = 0.f;
            #pragma unroll
            for (int ctl = 0; ctl < 4; ++ctl) {
                const float x = acc[rt][ctl][reg] + b1v[ctl];
                const float t = 1.f - 2.f / (__expf(2.f * x) + 1.f);
                s = fmaf(t, w2v[ctl], s);
            }
            sc[rt][reg] = s;
        }
    }
    #pragma unroll
    for (int off = 1; off < 16; off <<= 1)
        #pragma unroll
        for (int rt = 0; rt < 2; ++rt)
            #pragma unroll
            for (int reg = 0; reg < 4; ++reg)
                sc[rt][reg] += __shfl_xor(sc[rt][reg], off);

    if ((lane & 15) == 0) {
        #pragma unroll
        for (int rt = 0; rt < 2; ++rt)
            #pragma unroll
            for (int reg = 0; reg < 4; ++reg)
                sp[wave][rt * 16 + (lane >> 4) * 4 + reg] = sc[rt][reg];
    }
    __syncthreads();
    if (tid < TROWS)
        scL[tid] = __expf(sp[0][tid] + sp[1][tid] + sp[2][tid] + sp[3][tid] + b2[0]);
    __syncthreads();

    // ---- 4. PV from LDS; accL combine; per-block atomics per gap ----
    int g_lo, g_hi;
    {
        int node = t0;
        if (node < offL[0]) g_lo = -1;
        else {
            int lo = 0, hi = BATCH - 1;
            while (lo < hi) { int mid = (lo + hi + 1) >> 1; if (offL[mid] <= node) lo = mid; else hi = mid - 1; }
            g_lo = lo;
        }
        node = t0 + TROWS - 1;
        if (node < offL[0]) g_hi = -1;
        else {
            int lo = 0, hi = BATCH - 1;
            while (lo < hi) { int mid = (lo + hi + 1) >> 1; if (offL[mid] <= node) lo = mid; else hi = mid - 1; }
            g_hi = lo;
        }
    }

    for (int g = (g_lo < 0 ? 0 : g_lo); g <= g_hi; ++g) {
        const int rs = max(t0, offL[g]);
        const int re = min(t0 + TROWS, (g == BATCH - 1) ? N_NODES : offL[g + 1]);

        float4 a4 = {0.f, 0.f, 0.f, 0.f};
        float z = 0.f;
        for (int i = rs + wave; i < re; i += 4) {
            const int r = i - t0;
            const float p = scL[r];
            const int byte = r * 512 + ((((lane >> 1) ^ (r & 7))) << 4) + (lane & 1) * 8;
            half4 xv = *reinterpret_cast<const half4*>(
                reinterpret_cast<const char*>(Xs) + byte);
            a4.x = fmaf(p, (float)xv[0], a4.x);
            a4.y = fmaf(p, (float)xv[1], a4.y);
            a4.z = fmaf(p, (float)xv[2], a4.z);
            a4.w = fmaf(p, (float)xv[3], a4.w);
            z += p;
        }
        reinterpret_cast<float4*>(&accL[wave][0])[lane] = a4;
        if (lane == 0) zLs[wave] = z;
        __syncthreads();
        const float v = accL[0][tid] + accL[1][tid] + accL[2][tid] + accL[3][tid];
        atomicAdd(&pacc[g * H + tid], v);
        if (tid == 0) atomicAdd(&pz[g], zLs[0] + zLs[1] + zLs[2] + zLs[3]);
        __syncthreads();   // accL reused by next gap
    }
}

// ---------------------------------------------------------------------------
// Reduce: segment b = union of gaps [max(b-1,0), min(b+1,127)].
// out = sum(acc_g) / sum(z_g). 128 blocks x 256 threads.
// ---------------------------------------------------------------------------
__global__ __launch_bounds__(256) void reduce_kernel(
    const float* __restrict__ pacc, const float* __restrict__ pz,
    float* __restrict__ out)
{
    const int b = blockIdx.x;
    const int tid = threadIdx.x;
    const int g0 = (b == 0) ? 0 : b - 1;
    const int g1 = (b >= BATCH - 1) ? BATCH - 1 : b + 1;

    float r = 0.f, z = 0.f;
    for (int g = g0; g <= g1; ++g) {
        r += pacc[g * H + tid];
        z += pz[g];
    }
    out[b * H + tid] = r / z;
}

// ---------------------------------------------------------------------------
extern "C" void kernel_launch(void* const* d_in, const int* in_sizes, int n_in,
                              void* d_out, int out_size, void* d_ws, size_t ws_size,
                              hipStream_t stream)
{
    const float* X     = (const float*)d_in[0];
    const int* offs    = (const int*)d_in[1];   // int64 in ref -> int32 on device
    const float* W1    = (const float*)d_in[2];
    const float* b1    = (const float*)d_in[3];
    const float* W2    = (const float*)d_in[4];
    const float* b2    = (const float*)d_in[5];
    float* out         = (float*)d_out;

    // workspace layout (floats):
    //   [0, 32768)        pacc   (128 gaps x 256)
    //   [32768, 32896)    pz     (128)
    //   [32896, ...)      W1p    (65536 f16 = 128 KB)
    float* pacc   = (float*)d_ws;
    float* pz     = pacc + BATCH * H;
    _Float16* W1p = (_Float16*)(pz + BATCH);

    prep_kernel<<<160, 256, 0, stream>>>(W1, W1p, pacc, pz);
    fused_kernel<<<NTILES, 256, 0, stream>>>(X, W1p, b1, W2, b2, offs, pacc, pz);
    reduce_kernel<<<BATCH, 256, 0, stream>>>(pacc, pz, out);
}